// Round 6
// baseline (108.127 us; speedup 1.0000x reference)
//
#include <hip/hip_runtime.h>

#define ND 512   // directions
#define NP 64    // points per ray
#define NR 32    // rank
#define NF 256   // virtual subcarriers

#define PLANE (ND * NP * NR)       // 1,048,576 ushorts per A-plane
#define BOFF  (6 * PLANE)          // freq planes start here (ushort offset)
// ws usage: 6 A-planes + 3 B-planes = (6*1048576 + 3*8192)*2 B ~= 12.6 MB

typedef __attribute__((ext_vector_type(8))) short bf16x8;   // 8 bf16 = 4 VGPRs
typedef __attribute__((ext_vector_type(4))) float f32x4;

// float -> bf16 (RNE); inputs are finite.
__device__ inline unsigned short f2bf(float x) {
    unsigned u = __builtin_bit_cast(unsigned, x);
    u += 0x7FFFu + ((u >> 16) & 1u);
    return (unsigned short)(u >> 16);
}
__device__ inline unsigned pack2(float a, float b) {
    return (unsigned)f2bf(a) | ((unsigned)f2bf(b) << 16);
}

// ---------------- k1: prep (streaming, no barriers) ----------------
// Plane 0..3: att_re, att_im, rad_re, rad_im (bf16, natural [d][p][r]).
// Plane 4: cum_re, plane 5: -cum_im (p=0 row zeroed -> second-order term's
// p>=1 restriction is automatic; negation lets k2 use one conj pattern).
// B planes at BOFF: 0=vr, 1=vi, 2=vn(-vr), each [f][r] bf16.
__global__ __launch_bounds__(256, 2) void lrrt_prep_kernel(
    const float* __restrict__ att_re, const float* __restrict__ att_im,
    const float* __restrict__ rad_re, const float* __restrict__ rad_im,
    const float* __restrict__ freq_re, const float* __restrict__ freq_im,
    unsigned short* __restrict__ ws)
{
    const int t = threadIdx.x;
    const int d = blockIdx.x;
    const size_t base = (size_t)d * (NP * NR);

    // stage att/rad as bf16 (coalesced float4 -> uint2)
#pragma unroll
    for (int it = 0; it < 2; ++it) {
        const size_t g = base + (size_t)(t + it * 256) * 4;
        float4 x;
        x = *(const float4*)(att_re + g);
        *(uint2*)(ws + 0 * PLANE + g) = make_uint2(pack2(x.x, x.y), pack2(x.z, x.w));
        x = *(const float4*)(att_im + g);
        *(uint2*)(ws + 1 * PLANE + g) = make_uint2(pack2(x.x, x.y), pack2(x.z, x.w));
        x = *(const float4*)(rad_re + g);
        *(uint2*)(ws + 2 * PLANE + g) = make_uint2(pack2(x.x, x.y), pack2(x.z, x.w));
        x = *(const float4*)(rad_im + g);
        *(uint2*)(ws + 3 * PLANE + g) = make_uint2(pack2(x.x, x.y), pack2(x.z, x.w));
    }

    // cumsum of (non-conjugated) att along p; 64 threads, one rank column each
    if (t < 64) {
        const int r = t & 31;
        const int reim = t >> 5;
        const float* src = reim ? att_im : att_re;
        const float sgn = reim ? -1.f : 1.f;   // store -cum_im
        unsigned short* dst = ws + (size_t)(4 + reim) * PLANE + base;
        float run = src[base + r];
        dst[r] = 0;                            // p = 0 excluded
#pragma unroll
        for (int p = 1; p < NP; ++p) {
            run += src[base + (size_t)p * NR + r];
            dst[(size_t)p * NR + r] = f2bf(sgn * run);
        }
    }

    // bf16 freq planes (done by blocks 0..2; tiny)
    if (d < 3) {
        const float* src = (d == 1) ? freq_im : freq_re;
        const float sgn = (d == 2) ? -1.f : 1.f;
        unsigned short* dst = ws + BOFF + (size_t)d * (NF * NR);
        for (int i = t; i < NF * NR; i += 256) dst[i] = f2bf(sgn * src[i]);
    }
}

// ---------------- k2: pure MFMA GEMM + combine ----------------
// One block per direction d; wave wv owns p-rows 16wv..16wv+15 and loops all
// 16 n-tiles. A-frags load straight from ws (natural [p][r] row = 64 B, the
// wave's 6x1KB reads are perfectly coalesced). Chained-MFMA conj pattern:
//   re = mfma(x_i, vi, mfma(x_r, vr, 0)),  im = mfma(x_i, vn, mfma(x_r, vi, 0))
__global__ __launch_bounds__(256, 4) void lrrt_gemm_kernel(
    const unsigned short* __restrict__ ws, const int* __restrict__ mrl,
    float* __restrict__ out)
{
    __shared__ float s_red[4][NF][2];   // 8 KB cross-wave reduce

    const int t = threadIdx.x;
    const int d = blockIdx.x;
    const int lane = t & 63, wv = t >> 6, kg = lane >> 4, m_lo = lane & 15;

    const size_t arow = (size_t)d * (NP * NR) + (size_t)(wv * 16 + m_lo) * NR + 8 * kg;
    const bf16x8 a_r = *(const bf16x8*)(ws + 0 * PLANE + arow);
    const bf16x8 a_i = *(const bf16x8*)(ws + 1 * PLANE + arow);
    const bf16x8 r_r = *(const bf16x8*)(ws + 2 * PLANE + arow);
    const bf16x8 r_i = *(const bf16x8*)(ws + 3 * PLANE + arow);
    const bf16x8 c_r = *(const bf16x8*)(ws + 4 * PLANE + arow);
    const bf16x8 c_i = *(const bf16x8*)(ws + 5 * PLANE + arow);

    const float dt = (float)(*mrl) / (float)NP;
    const f32x4 zero = {0.f, 0.f, 0.f, 0.f};

#pragma unroll 1
    for (int q = 0; q < 16; ++q) {
        const size_t brow = (size_t)(16 * q + m_lo) * NR + 8 * kg;
        const bf16x8 vr = *(const bf16x8*)(ws + BOFF + brow);
        const bf16x8 vi = *(const bf16x8*)(ws + BOFF + NF * NR + brow);
        const bf16x8 vn = *(const bf16x8*)(ws + BOFF + 2 * NF * NR + brow);

        f32x4 Are = __builtin_amdgcn_mfma_f32_16x16x32_bf16(a_r, vr, zero, 0, 0, 0);
        f32x4 Aim = __builtin_amdgcn_mfma_f32_16x16x32_bf16(a_r, vi, zero, 0, 0, 0);
        f32x4 Bre = __builtin_amdgcn_mfma_f32_16x16x32_bf16(r_r, vr, zero, 0, 0, 0);
        f32x4 Bim = __builtin_amdgcn_mfma_f32_16x16x32_bf16(r_r, vi, zero, 0, 0, 0);
        f32x4 Ure = __builtin_amdgcn_mfma_f32_16x16x32_bf16(c_r, vr, zero, 0, 0, 0);
        f32x4 Uim = __builtin_amdgcn_mfma_f32_16x16x32_bf16(c_r, vi, zero, 0, 0, 0);
        Are = __builtin_amdgcn_mfma_f32_16x16x32_bf16(a_i, vi, Are, 0, 0, 0);
        Aim = __builtin_amdgcn_mfma_f32_16x16x32_bf16(a_i, vn, Aim, 0, 0, 0);
        Bre = __builtin_amdgcn_mfma_f32_16x16x32_bf16(r_i, vi, Bre, 0, 0, 0);
        Bim = __builtin_amdgcn_mfma_f32_16x16x32_bf16(r_i, vn, Bim, 0, 0, 0);
        Ure = __builtin_amdgcn_mfma_f32_16x16x32_bf16(c_i, vi, Ure, 0, 0, 0);
        Uim = __builtin_amdgcn_mfma_f32_16x16x32_bf16(c_i, vn, Uim, 0, 0, 0);

        float sr = 0.f, si = 0.f;
#pragma unroll
        for (int i = 0; i < 4; ++i) {
            const float qre = Bre[i] * Are[i] - Bim[i] * Aim[i];
            const float qim = Bre[i] * Aim[i] + Bim[i] * Are[i];
            const float cre = fmaf(dt, Ure[i], 1.0f);   // 1 + dt*u_re
            const float cim = dt * Uim[i];              // dt*u_im
            sr = fmaf(qre, cre, fmaf(-qim, cim, sr));
            si = fmaf(qim, cre, fmaf(qre, cim, si));
        }
        // reduce over the 4 row-groups (p within the wave's strip)
        sr += __shfl_xor(sr, 16, 64); si += __shfl_xor(si, 16, 64);
        sr += __shfl_xor(sr, 32, 64); si += __shfl_xor(si, 32, 64);
        if (lane < 16) {
            s_red[wv][16 * q + lane][0] = sr;
            s_red[wv][16 * q + lane][1] = si;
        }
    }
    __syncthreads();

    // cross-wave sum + one atomic pair per f per block (planar out)
    const float scale = dt / (float)ND;
    const int f = t;
    const float re = s_red[0][f][0] + s_red[1][f][0] + s_red[2][f][0] + s_red[3][f][0];
    const float im = s_red[0][f][1] + s_red[1][f][1] + s_red[2][f][1] + s_red[3][f][1];
    atomicAdd(&out[f], re * scale);
    atomicAdd(&out[NF + f], im * scale);
}

extern "C" void kernel_launch(void* const* d_in, const int* in_sizes, int n_in,
                              void* d_out, int out_size, void* d_ws, size_t ws_size,
                              hipStream_t stream) {
    const float* att_re = (const float*)d_in[0];
    const float* att_im = (const float*)d_in[1];
    const float* rad_re = (const float*)d_in[2];
    const float* rad_im = (const float*)d_in[3];
    const float* freq_re = (const float*)d_in[4];
    const float* freq_im = (const float*)d_in[5];
    const int* mrl = (const int*)d_in[6];
    float* out = (float*)d_out;
    unsigned short* ws = (unsigned short*)d_ws;

    // d_out is poisoned 0xAA before every launch; we accumulate with atomics.
    hipMemsetAsync(d_out, 0, (size_t)out_size * sizeof(float), stream);

    lrrt_prep_kernel<<<ND, 256, 0, stream>>>(
        att_re, att_im, rad_re, rad_im, freq_re, freq_im, ws);
    lrrt_gemm_kernel<<<ND, 256, 0, stream>>>(ws, mrl, out);
}

// Round 7
// 96.741 us; speedup vs baseline: 1.1177x; 1.1177x over previous
//
#include <hip/hip_runtime.h>

#define ND 512   // directions
#define NP 64    // points per ray
#define NR 32    // rank
#define NF 256   // virtual subcarriers
#define RS 40    // ushorts per LDS row (80 B): bank pattern repeats /8 rows -> 2-way only

typedef __attribute__((ext_vector_type(8))) short bf16x8;   // 8 bf16 = 4 VGPRs
typedef __attribute__((ext_vector_type(4))) float f32x4;
typedef __attribute__((ext_vector_type(4))) unsigned int uint4v;

// float -> bf16 (RNE); inputs are finite.
__device__ inline unsigned short f2bf(float x) {
    unsigned u = __builtin_bit_cast(unsigned, x);
    u += 0x7FFFu + ((u >> 16) & 1u);
    return (unsigned short)(u >> 16);
}
__device__ inline unsigned pack2(float a, float b) {
    return (unsigned)f2bf(a) | ((unsigned)f2bf(b) << 16);
}
// negate 8 packed bf16 (sign-bit XOR)
__device__ inline bf16x8 neg8(bf16x8 v) {
    uint4v u = __builtin_bit_cast(uint4v, v);
    u ^= (uint4v){0x80008000u, 0x80008000u, 0x80008000u, 0x80008000u};
    return __builtin_bit_cast(bf16x8, u);
}

// ---- tiny prep: bf16 freq planes into ws (vr at 0, vi at 8192 ushorts) ----
__global__ __launch_bounds__(256) void lrrt_bprep_kernel(
    const float* __restrict__ fre, const float* __restrict__ fim,
    unsigned short* __restrict__ ws)
{
    const int tid = blockIdx.x * 256 + threadIdx.x;   // 0..4095
    const int plane = tid >> 11;                      // 0=vr 1=vi
    const int i4 = (tid & 2047) * 4;
    const float* src = plane ? fim : fre;
    const float4 x = *(const float4*)(src + i4);
    *(uint2*)(ws + plane * (NF * NR) + i4) = make_uint2(pack2(x.x, x.y), pack2(x.z, x.w));
}

// ---- main: one block per (direction d, freq-half h); 4 waves ----
// Wave wv owns p-strip 16wv..16wv+15 (A-frag rows) and loops the half's 8
// n-tiles. Chained-MFMA conj pattern (verified R3-R6):
//   re = mfma(x_i, vi, mfma(x_r, vr, 0)),  im = mfma(x_i, -vr, mfma(x_r, vi, 0))
// cum planes store dt*cum_re and -dt*cum_im (p=0 row zeroed -> p>=1 automatic).
__global__ __launch_bounds__(256, 4) void lrrt_main_kernel(
    const float* __restrict__ att_re, const float* __restrict__ att_im,
    const float* __restrict__ rad_re, const float* __restrict__ rad_im,
    const unsigned short* __restrict__ wsB, const int* __restrict__ mrl,
    float* __restrict__ out)
{
    __shared__ __align__(16) unsigned short s_a[6][NP * RS];  // 30720 B
    __shared__ float s_tot[256];                              // 1 KB
    __shared__ float s_red[4][128][2];                        // 4 KB

    const int t = threadIdx.x;
    const int h = blockIdx.x & 1;
    const int d = blockIdx.x >> 1;
    const size_t base = (size_t)d * (NP * NR);
    const int lane = t & 63, wv = t >> 6, kg = lane >> 4, m_lo = lane & 15;
    const float dt = (float)(*mrl) / (float)NP;

    // --- 1a. stage att/rad bf16 into padded LDS (coalesced float4) ---
#pragma unroll
    for (int half = 0; half < 2; ++half) {
        const int w = t + half * 256;        // float4 index 0..511
        const int p = w >> 3;
        const int c = (w & 7) * 4;
        const size_t g = base + (size_t)p * NR + c;
        const int lo = p * RS + c;
        float4 x;
        x = *(const float4*)(att_re + g);
        *(uint2*)&s_a[0][lo] = make_uint2(pack2(x.x, x.y), pack2(x.z, x.w));
        x = *(const float4*)(att_im + g);
        *(uint2*)&s_a[1][lo] = make_uint2(pack2(x.x, x.y), pack2(x.z, x.w));
        x = *(const float4*)(rad_re + g);
        *(uint2*)&s_a[2][lo] = make_uint2(pack2(x.x, x.y), pack2(x.z, x.w));
        x = *(const float4*)(rad_im + g);
        *(uint2*)&s_a[3][lo] = make_uint2(pack2(x.x, x.y), pack2(x.z, x.w));
    }

    // --- 1b. segmented cumsum of att along p (seg = wave strip) ---
    const int cs_r = t & 31, cs_reim = (t >> 5) & 1, cs_seg = t >> 6;
    float vals[16];
    {
        const float* src = cs_reim ? att_im : att_re;
        float run = 0.f;
#pragma unroll
        for (int i = 0; i < 16; ++i) {
            run += src[base + (size_t)(cs_seg * 16 + i) * NR + cs_r];
            vals[i] = run;
        }
        s_tot[t] = run;
    }
    __syncthreads();

    // --- 1c. add segment offsets; store dt*cum_re / -dt*cum_im; zero p=0 ---
    {
        float off = 0.f;
#pragma unroll
        for (int s = 0; s < 3; ++s)
            if (s < cs_seg) off += s_tot[s * 64 + cs_reim * 32 + cs_r];
        const float sc = cs_reim ? -dt : dt;
        unsigned short* dst = s_a[4 + cs_reim];
#pragma unroll
        for (int i = 0; i < 16; ++i) {
            const int p = cs_seg * 16 + i;
            dst[p * RS + cs_r] = (p == 0) ? (unsigned short)0
                                          : f2bf(sc * (vals[i] + off));
        }
    }
    __syncthreads();

    // --- 2. A fragments for this wave's p-strip (b128, 2-way banks = free) ---
    const int aoff = (wv * 16 + m_lo) * RS + 8 * kg;
    const bf16x8 a_r = *(const bf16x8*)&s_a[0][aoff];
    const bf16x8 a_i = *(const bf16x8*)&s_a[1][aoff];
    const bf16x8 r_r = *(const bf16x8*)&s_a[2][aoff];
    const bf16x8 r_i = *(const bf16x8*)&s_a[3][aoff];
    const bf16x8 c_r = *(const bf16x8*)&s_a[4][aoff];
    const bf16x8 c_i = *(const bf16x8*)&s_a[5][aoff];

    const f32x4 zero = {0.f, 0.f, 0.f, 0.f};

    // --- 3. loop the half's 8 n-tiles; B frags pre-converted bf16 from ws ---
#pragma unroll 1
    for (int q = 0; q < 8; ++q) {
        const int f = 16 * (8 * h + q) + m_lo;
        const size_t boff = (size_t)f * NR + 8 * kg;
        const bf16x8 vr = *(const bf16x8*)(wsB + boff);
        const bf16x8 vi = *(const bf16x8*)(wsB + NF * NR + boff);
        const bf16x8 vn = neg8(vr);

        f32x4 Are = __builtin_amdgcn_mfma_f32_16x16x32_bf16(a_r, vr, zero, 0, 0, 0);
        f32x4 Aim = __builtin_amdgcn_mfma_f32_16x16x32_bf16(a_r, vi, zero, 0, 0, 0);
        f32x4 Bre = __builtin_amdgcn_mfma_f32_16x16x32_bf16(r_r, vr, zero, 0, 0, 0);
        f32x4 Bim = __builtin_amdgcn_mfma_f32_16x16x32_bf16(r_r, vi, zero, 0, 0, 0);
        f32x4 Ure = __builtin_amdgcn_mfma_f32_16x16x32_bf16(c_r, vr, zero, 0, 0, 0);
        f32x4 Uim = __builtin_amdgcn_mfma_f32_16x16x32_bf16(c_r, vi, zero, 0, 0, 0);
        Are = __builtin_amdgcn_mfma_f32_16x16x32_bf16(a_i, vi, Are, 0, 0, 0);
        Aim = __builtin_amdgcn_mfma_f32_16x16x32_bf16(a_i, vn, Aim, 0, 0, 0);
        Bre = __builtin_amdgcn_mfma_f32_16x16x32_bf16(r_i, vi, Bre, 0, 0, 0);
        Bim = __builtin_amdgcn_mfma_f32_16x16x32_bf16(r_i, vn, Bim, 0, 0, 0);
        Ure = __builtin_amdgcn_mfma_f32_16x16x32_bf16(c_i, vi, Ure, 0, 0, 0);
        Uim = __builtin_amdgcn_mfma_f32_16x16x32_bf16(c_i, vn, Uim, 0, 0, 0);

        float sr = 0.f, si = 0.f;
#pragma unroll
        for (int i = 0; i < 4; ++i) {
            const float qre = Bre[i] * Are[i] - Bim[i] * Aim[i];
            const float qim = Bre[i] * Aim[i] + Bim[i] * Are[i];
            const float cre = 1.0f + Ure[i];   // dt already folded into cum
            const float cim = Uim[i];
            sr = fmaf(qre, cre, fmaf(-qim, cim, sr));
            si = fmaf(qim, cre, fmaf(qre, cim, si));
        }
        // reduce over the 4 row-groups (p within the wave's strip)
        sr += __shfl_xor(sr, 16, 64); si += __shfl_xor(si, 16, 64);
        sr += __shfl_xor(sr, 32, 64); si += __shfl_xor(si, 32, 64);
        if (lane < 16) {
            s_red[wv][16 * q + lane][0] = sr;
            s_red[wv][16 * q + lane][1] = si;
        }
    }
    __syncthreads();

    // --- 4. cross-wave sum; one atomic per (f, comp) per block (planar) ---
    const float scale = dt / (float)ND;
    {
        const int lf = t >> 1, comp = t & 1;
        const float v = s_red[0][lf][comp] + s_red[1][lf][comp]
                      + s_red[2][lf][comp] + s_red[3][lf][comp];
        atomicAdd(&out[comp * NF + h * 128 + lf], v * scale);
    }
}

extern "C" void kernel_launch(void* const* d_in, const int* in_sizes, int n_in,
                              void* d_out, int out_size, void* d_ws, size_t ws_size,
                              hipStream_t stream) {
    const float* att_re = (const float*)d_in[0];
    const float* att_im = (const float*)d_in[1];
    const float* rad_re = (const float*)d_in[2];
    const float* rad_im = (const float*)d_in[3];
    const float* freq_re = (const float*)d_in[4];
    const float* freq_im = (const float*)d_in[5];
    const int* mrl = (const int*)d_in[6];
    float* out = (float*)d_out;
    unsigned short* ws = (unsigned short*)d_ws;

    // d_out is poisoned 0xAA before every launch; we accumulate with atomics.
    hipMemsetAsync(d_out, 0, (size_t)out_size * sizeof(float), stream);

    lrrt_bprep_kernel<<<16, 256, 0, stream>>>(freq_re, freq_im, ws);
    lrrt_main_kernel<<<2 * ND, 256, 0, stream>>>(
        att_re, att_im, rad_re, rad_im, ws, mrl, out);
}